// Round 13
// baseline (189.129 us; speedup 1.0000x reference)
//
#include <hip/hip_runtime.h>
#include <hip/hip_bf16.h>

#define NPTS 4096
#define BATCH 4
#define KNN 20

typedef __attribute__((ext_vector_type(8))) short bf16x8;
typedef __attribute__((ext_vector_type(4))) float f32x4;
typedef __attribute__((ext_vector_type(4))) int i32x4;
typedef unsigned long long u64;

// ws layout (bytes):
//   0      : fp32 tables: w0s[384] b0[64] s1[64] b1[64] wouts[192] bout[3]
//   4096   : whi frags ushort[24576]  (B-fragment layout, hi split)
//   53248  : wlo frags ushort[24576]  (lo split)
//   102400 : idxbuf ushort[16384*20]  (655360 B)
//   757760 : xq float4[16384] = (x0,x1,x2,||x||^2)
#define OFF_W0S   0
#define OFF_B0F   384
#define OFF_S1F   448
#define OFF_B1F   512
#define OFF_WOUTS 576
#define OFF_BOUTF 768
#define OFF_WHI_BYTES 4096
#define OFF_WLO_BYTES 53248
#define OFF_IDX_BYTES 102400
#define OFF_XQ_BYTES  757760

__device__ __forceinline__ u64 shflx64(u64 v, int off) {
  int lo = __shfl_xor((int)(v & 0xFFFFFFFFull), off);
  int hi = __shfl_xor((int)(v >> 32), off);
  return ((u64)(unsigned)hi << 32) | (unsigned)lo;
}
__device__ __forceinline__ u64 shflbc64(u64 v, int src) {
  int lo = __shfl((int)(v & 0xFFFFFFFFull), src);
  int hi = __shfl((int)(v >> 32), src);
  return ((u64)(unsigned)hi << 32) | (unsigned)lo;
}

__global__ __launch_bounds__(256) void prep_kernel(
    const float* __restrict__ x,
    const float* __restrict__ w0, const float* __restrict__ g0, const float* __restrict__ b0,
    const float* __restrict__ w1, const float* __restrict__ g1, const float* __restrict__ b1,
    const float* __restrict__ wout, const float* __restrict__ gout, const float* __restrict__ bout,
    float* __restrict__ wsf, unsigned short* __restrict__ whi, unsigned short* __restrict__ wlo,
    float4* __restrict__ xq) {
  const float rs = 1.0f / sqrtf(1.0f + 1e-5f);
  int t = blockIdx.x * 256 + threadIdx.x;
  if (t < 384) wsf[OFF_W0S + t] = w0[t] * (g0[t / 6] * rs);
  if (t < 64) {
    wsf[OFF_B0F + t] = b0[t];
    wsf[OFF_S1F + t] = g1[t] * rs;
    wsf[OFF_B1F + t] = b1[t];
  }
  if (t < 192) wsf[OFF_WOUTS + t] = wout[t] * (gout[t / 64] * rs);
  if (t < 3) wsf[OFF_BOUTF + t] = bout[t];
  if (t < BATCH * NPTS) {
    int bb = t >> 12, j = t & (NPTS - 1);
    const float* xb = x + bb * 3 * NPTS;
    float x0 = xb[j], x1 = xb[NPTS + j], x2 = xb[2 * NPTS + j];
    float xx = x0 * x0 + x1 * x1 + x2 * x2;
    xq[t] = make_float4(x0, x1, x2, xx);
  }
  // B-fragment layout for mfma_f32_16x16x32_bf16: frag ft = kk*4+nt; lane L holds
  // B[k = kk*32 + (L>>4)*8 + j][n = nt*16 + (L&15)], j packed consecutively.
  if (t < 24576) {
    int j = t & 7, L = (t >> 3) & 63, ft = t >> 9;
    int kk = ft >> 2, nt = ft & 3;
    int k = kk * 32 + ((L >> 4) << 3) + j;
    int c = k >> 6, d = k & 63;
    int o = nt * 16 + (L & 15);
    float w = w1[(o * 6 + c) * 64 + d];
    unsigned bw = __float_as_uint(w);
    unsigned hb = bw & 0xFFFF0000u;
    float r = w - __uint_as_float(hb);
    whi[t] = (unsigned short)(bw >> 16);
    wlo[t] = (unsigned short)(__float_as_uint(r) >> 16);
  }
}

// knn v2.1 (R10 exact config — best measured 78.2 µs): single-scan register
// top-2 cache, u64 keys, butterfly argmax, unroll 8.
__global__ __launch_bounds__(64, 4) void knn_kernel(const float4* __restrict__ xq,
                                                    unsigned short* __restrict__ idxbuf) {
  const int pt = blockIdx.x;
  const int b = pt >> 12, n = pt & (NPTS - 1);
  const int lane = threadIdx.x;
  const float4* xqb = xq + b * NPTS;
  const float4 xin = xqb[n];
  const float xi0 = xin.x, xi1 = xin.y, xi2 = xin.z;
  const float nxxi = -xin.w;

  u64 k1 = 0, k2 = 0;
  unsigned lo = 4095u - (unsigned)lane;
#pragma unroll 8
  for (int s = 0; s < 64; ++s) {
    float4 q = xqb[s * 64 + lane];
    float dot = xi0 * q.x + xi1 * q.y + xi2 * q.z;
    float pd = fmaf(2.0f, dot, nxxi) - q.w;   // bit-identical to ref expr
    u64 k = ((u64)(~__float_as_uint(pd)) << 32) | lo;
    lo -= 64u;
    bool c1 = k > k1;
    bool c2 = k > k2;
    u64 t = c1 ? k1 : k;
    k2 = c2 ? t : k2;
    k1 = c1 ? k : k1;
  }

  u64 tk = 0;
  unsigned myout = 0;
#pragma unroll 1
  for (int r = 0; r < KNN; ++r) {
    u64 bk = k1;
    for (int off = 32; off > 0; off >>= 1) {
      u64 ok = shflx64(bk, off);
      if (ok > bk) bk = ok;
    }
    unsigned bj = 4095u - (unsigned)(bk & 4095u);
    if (lane == r) myout = bj;
    bool owner = (k1 == bk);
    u64 bit = 1ull << (bj >> 6);
    if (owner) {
      tk |= bit;
      k1 = k2;
      k2 = 0;
    }
    bool need = owner && (k1 == 0);
    u64 nm = __ballot(need);
    if (nm) {
      int LN = __ffsll(nm) - 1;
      int j2 = lane * 64 + LN;
      float4 q = xqb[j2];
      float dot = xi0 * q.x + xi1 * q.y + xi2 * q.z;
      float pd = fmaf(2.0f, dot, nxxi) - q.w;
      u64 kk = ((u64)(~__float_as_uint(pd)) << 32) | (4095u - (unsigned)j2);
      u64 tkl = shflbc64(tk, LN);
      if ((tkl >> lane) & 1) kk = 0;
      u64 w1k = kk;
      for (int off = 32; off > 0; off >>= 1) {
        u64 ok = shflx64(w1k, off);
        if (ok > w1k) w1k = ok;
      }
      u64 kk2 = (kk == w1k) ? 0 : kk;
      u64 w2k = kk2;
      for (int off = 32; off > 0; off >>= 1) {
        u64 ok = shflx64(w2k, off);
        if (ok > w2k) w2k = ok;
      }
      if (lane == LN) { k1 = w1k; k2 = w2k; }
    }
  }
  if (lane < KNN) idxbuf[pt * KNN + lane] = (unsigned short)myout;
}

// mlp v4.1: R10's v4 body EXACTLY, but __launch_bounds__(64,1) — the single
// variable under test. (64,2) caps unified VGPR+AGPR at 256; if v4's true
// demand exceeds that, the k-loop spills to scratch (invisible: mlp never
// surfaces in top-5). (64,1) lets the allocator take what it needs, trading
// at worst 2->1 waves/SIMD for zero spill.
__global__ __launch_bounds__(64, 1) void mlp_kernel(const float4* __restrict__ xq,
                                                    const float* __restrict__ wsf,
                                                    const unsigned short* __restrict__ whi,
                                                    const unsigned short* __restrict__ wlo,
                                                    const unsigned short* __restrict__ idxbuf,
                                                    float* __restrict__ out) {
  __shared__ float w0l[448];
  __shared__ float v6l[80 * 12];
  __shared__ float pmax[20 * 66];

  const int lane = threadIdx.x;
  const int quad = lane >> 4, l15 = lane & 15;
  const int pt_base = blockIdx.x * 4;

  const i32x4* whp = (const i32x4*)whi;
  const i32x4* wlp = (const i32x4*)wlo;

  i32x4 wh[4], wl[4];
#pragma unroll
  for (int nt = 0; nt < 4; ++nt) {
    wh[nt] = whp[nt * 64 + lane];
    wl[nt] = wlp[nt * 64 + lane];
  }

  for (int i = lane; i < 448; i += 64) w0l[i] = wsf[i];

#pragma unroll
  for (int rep = 0; rep < 2; ++rep) {
    int e = rep * 64 + lane;
    if (e < 80) {
      int p = e / 20, el = e - p * 20;
      int pt = pt_base + p;
      int b = pt >> 12, n = pt & (NPTS - 1);
      float4 xi = xq[b * NPTS + n];
      int jn = idxbuf[pt * KNN + el];
      float4 xj = xq[b * NPTS + jn];
      v6l[e * 12 + 0] = xj.x - xi.x;
      v6l[e * 12 + 1] = xj.y - xi.y;
      v6l[e * 12 + 2] = xj.z - xi.z;
      v6l[e * 12 + 3] = xi.x;
      v6l[e * 12 + 4] = xi.y;
      v6l[e * 12 + 5] = xi.z;
    }
  }
  __syncthreads();

  f32x4 acc[5][4];
#pragma unroll
  for (int t = 0; t < 5; ++t)
#pragma unroll
    for (int nt = 0; nt < 4; ++nt) acc[t][nt] = (f32x4){0.f, 0.f, 0.f, 0.f};

#pragma unroll 1
  for (int hh = 0; hh < 2; ++hh) {
    float v6r[5][6];
#pragma unroll
    for (int t = 0; t < 5; ++t) {
      const float* vr = v6l + (t * 16 + l15) * 12;
      f32x4 a4 = *(const f32x4*)vr;
      v6r[t][0] = a4.x; v6r[t][1] = a4.y; v6r[t][2] = a4.z; v6r[t][3] = a4.w;
      v6r[t][4] = vr[4]; v6r[t][5] = vr[5];
    }
    float hf[5][8];
#pragma unroll
    for (int j = 0; j < 8; ++j) {
      const int d = hh * 32 + quad * 8 + j;
      const float* wr = w0l + d * 6;
      float wc0 = wr[0], wc1 = wr[1], wc2 = wr[2];
      float wc3 = wr[3], wc4 = wr[4], wc5 = wr[5];
      float bb = w0l[384 + d];
#pragma unroll
      for (int t = 0; t < 5; ++t) {
        float a = bb + wc0 * v6r[t][0] + wc1 * v6r[t][1] + wc2 * v6r[t][2]
                     + wc3 * v6r[t][3] + wc4 * v6r[t][4] + wc5 * v6r[t][5];
        hf[t][j] = fmaxf(a, 0.2f * a);
      }
    }

#pragma unroll 1
    for (int cc = 0; cc < 6; ++cc) {
      const int kk = cc * 2 + hh;
      const bool hasnext = !(hh == 1 && cc == 5);
      const int kkn = (cc < 5) ? kk + 2 : 1;
      i32x4 whn[4], wln[4];
      if (hasnext) {
#pragma unroll
        for (int nt = 0; nt < 4; ++nt) {
          whn[nt] = whp[(kkn * 4 + nt) * 64 + lane];
          wln[nt] = wlp[(kkn * 4 + nt) * 64 + lane];
        }
      }
#pragma unroll
      for (int t = 0; t < 5; ++t) {
        float vc = v6l[(t * 16 + l15) * 12 + cc];
        float u0 = vc * hf[t][0], u1 = vc * hf[t][1];
        float u2 = vc * hf[t][2], u3 = vc * hf[t][3];
        float u4 = vc * hf[t][4], u5 = vc * hf[t][5];
        float u6 = vc * hf[t][6], u7 = vc * hf[t][7];
        unsigned ub0 = __float_as_uint(u0), ub1 = __float_as_uint(u1);
        unsigned ub2 = __float_as_uint(u2), ub3 = __float_as_uint(u3);
        unsigned ub4 = __float_as_uint(u4), ub5 = __float_as_uint(u5);
        unsigned ub6 = __float_as_uint(u6), ub7 = __float_as_uint(u7);
        float r0 = u0 - __uint_as_float(ub0 & 0xFFFF0000u);
        float r1 = u1 - __uint_as_float(ub1 & 0xFFFF0000u);
        float r2 = u2 - __uint_as_float(ub2 & 0xFFFF0000u);
        float r3 = u3 - __uint_as_float(ub3 & 0xFFFF0000u);
        float r4 = u4 - __uint_as_float(ub4 & 0xFFFF0000u);
        float r5 = u5 - __uint_as_float(ub5 & 0xFFFF0000u);
        float r6 = u6 - __uint_as_float(ub6 & 0xFFFF0000u);
        float r7 = u7 - __uint_as_float(ub7 & 0xFFFF0000u);
        i32x4 ah, al;
        ah.x = __builtin_amdgcn_perm(ub1, ub0, 0x07060302);
        ah.y = __builtin_amdgcn_perm(ub3, ub2, 0x07060302);
        ah.z = __builtin_amdgcn_perm(ub5, ub4, 0x07060302);
        ah.w = __builtin_amdgcn_perm(ub7, ub6, 0x07060302);
        al.x = __builtin_amdgcn_perm(__float_as_uint(r1), __float_as_uint(r0), 0x07060302);
        al.y = __builtin_amdgcn_perm(__float_as_uint(r3), __float_as_uint(r2), 0x07060302);
        al.z = __builtin_amdgcn_perm(__float_as_uint(r5), __float_as_uint(r4), 0x07060302);
        al.w = __builtin_amdgcn_perm(__float_as_uint(r7), __float_as_uint(r6), 0x07060302);
        bf16x8 ahv = __builtin_bit_cast(bf16x8, ah);
        bf16x8 alv = __builtin_bit_cast(bf16x8, al);
#pragma unroll
        for (int nt = 0; nt < 4; ++nt) {
          bf16x8 bh = __builtin_bit_cast(bf16x8, wh[nt]);
          bf16x8 bl = __builtin_bit_cast(bf16x8, wl[nt]);
          acc[t][nt] = __builtin_amdgcn_mfma_f32_16x16x32_bf16(ahv, bh, acc[t][nt], 0, 0, 0);
          acc[t][nt] = __builtin_amdgcn_mfma_f32_16x16x32_bf16(ahv, bl, acc[t][nt], 0, 0, 0);
          acc[t][nt] = __builtin_amdgcn_mfma_f32_16x16x32_bf16(alv, bh, acc[t][nt], 0, 0, 0);
        }
      }
      if (hasnext) {
#pragma unroll
        for (int nt = 0; nt < 4; ++nt) { wh[nt] = whn[nt]; wl[nt] = wln[nt]; }
      }
    }
  }
  __syncthreads();

  float s1v[4], b1v[4];
#pragma unroll
  for (int nt = 0; nt < 4; ++nt) {
    s1v[nt] = wsf[OFF_S1F + nt * 16 + l15];
    b1v[nt] = wsf[OFF_B1F + nt * 16 + l15];
  }
#pragma unroll
  for (int t = 0; t < 5; ++t) {
#pragma unroll
    for (int nt = 0; nt < 4; ++nt) {
      f32x4 a = acc[t][nt];
      float z0 = a.x * s1v[nt] + b1v[nt]; z0 = fmaxf(z0, 0.2f * z0);
      float z1 = a.y * s1v[nt] + b1v[nt]; z1 = fmaxf(z1, 0.2f * z1);
      float z2 = a.z * s1v[nt] + b1v[nt]; z2 = fmaxf(z2, 0.2f * z2);
      float z3 = a.w * s1v[nt] + b1v[nt]; z3 = fmaxf(z3, 0.2f * z3);
      float m4 = fmaxf(fmaxf(z0, z1), fmaxf(z2, z3));
      pmax[(t * 4 + quad) * 66 + nt * 16 + l15] = m4;
    }
  }
  __syncthreads();

  float woutr[3];
#pragma unroll
  for (int m = 0; m < 3; ++m) woutr[m] = wsf[OFF_WOUTS + m * 64 + lane];
#pragma unroll
  for (int p = 0; p < 4; ++p) {
    float x1 = pmax[(p * 5 + 0) * 66 + lane];
    x1 = fmaxf(x1, pmax[(p * 5 + 1) * 66 + lane]);
    x1 = fmaxf(x1, pmax[(p * 5 + 2) * 66 + lane]);
    x1 = fmaxf(x1, pmax[(p * 5 + 3) * 66 + lane]);
    x1 = fmaxf(x1, pmax[(p * 5 + 4) * 66 + lane]);
    int pt = pt_base + p;
    int b = pt >> 12, n = pt & (NPTS - 1);
#pragma unroll
    for (int m = 0; m < 3; ++m) {
      float part = woutr[m] * x1;
      for (int off = 32; off > 0; off >>= 1) part += __shfl_xor(part, off);
      if (lane == 0) {
        float ov = part + wsf[OFF_BOUTF + m];
        out[(b * 3 + m) * NPTS + n] = fmaxf(ov, 0.2f * ov);
      }
    }
  }
}

extern "C" void kernel_launch(void* const* d_in, const int* in_sizes, int n_in,
                              void* d_out, int out_size, void* d_ws, size_t ws_size,
                              hipStream_t stream) {
  const float* x    = (const float*)d_in[0];
  const float* w0   = (const float*)d_in[1];
  const float* g0   = (const float*)d_in[2];
  const float* b0   = (const float*)d_in[3];
  const float* w1   = (const float*)d_in[4];
  const float* g1   = (const float*)d_in[5];
  const float* b1   = (const float*)d_in[6];
  const float* wout = (const float*)d_in[7];
  const float* gout = (const float*)d_in[8];
  const float* bout = (const float*)d_in[9];
  float* wsf = (float*)d_ws;
  unsigned short* whi = (unsigned short*)((char*)d_ws + OFF_WHI_BYTES);
  unsigned short* wlo = (unsigned short*)((char*)d_ws + OFF_WLO_BYTES);
  unsigned short* idxbuf = (unsigned short*)((char*)d_ws + OFF_IDX_BYTES);
  float4* xq = (float4*)((char*)d_ws + OFF_XQ_BYTES);
  float* out = (float*)d_out;

  prep_kernel<<<96, 256, 0, stream>>>(x, w0, g0, b0, w1, g1, b1, wout, gout, bout,
                                      wsf, whi, wlo, xq);
  knn_kernel<<<BATCH * NPTS, 64, 0, stream>>>(xq, idxbuf);
  mlp_kernel<<<BATCH * NPTS / 4, 64, 0, stream>>>(xq, wsf, whi, wlo, idxbuf, out);
}

// Round 14
// 176.994 us; speedup vs baseline: 1.0686x; 1.0686x over previous
//
#include <hip/hip_runtime.h>
#include <hip/hip_bf16.h>

#define NPTS 4096
#define BATCH 4
#define KNN 20

typedef __attribute__((ext_vector_type(8))) short bf16x8;
typedef __attribute__((ext_vector_type(4))) float f32x4;
typedef __attribute__((ext_vector_type(4))) int i32x4;
typedef unsigned long long u64;

// ws layout (bytes):
//   0      : fp32 tables: w0s[384] b0[64] s1[64] b1[64] wouts[192] bout[3]
//   4096   : whi frags ushort[24576]  (B-fragment layout, hi split)
//   53248  : wlo frags ushort[24576]  (lo split)
//   102400 : idxbuf ushort[16384*20]  (655360 B)
//   757760 : xq float4[16384] = (x0,x1,x2,||x||^2)
#define OFF_W0S   0
#define OFF_B0F   384
#define OFF_S1F   448
#define OFF_B1F   512
#define OFF_WOUTS 576
#define OFF_BOUTF 768
#define OFF_WHI_BYTES 4096
#define OFF_WLO_BYTES 53248
#define OFF_IDX_BYTES 102400
#define OFF_XQ_BYTES  757760

__device__ __forceinline__ u64 shflx64(u64 v, int off) {
  int lo = __shfl_xor((int)(v & 0xFFFFFFFFull), off);
  int hi = __shfl_xor((int)(v >> 32), off);
  return ((u64)(unsigned)hi << 32) | (unsigned)lo;
}
__device__ __forceinline__ u64 shflbc64(u64 v, int src) {
  int lo = __shfl((int)(v & 0xFFFFFFFFull), src);
  int hi = __shfl((int)(v >> 32), src);
  return ((u64)(unsigned)hi << 32) | (unsigned)lo;
}

__global__ __launch_bounds__(256) void prep_kernel(
    const float* __restrict__ x,
    const float* __restrict__ w0, const float* __restrict__ g0, const float* __restrict__ b0,
    const float* __restrict__ w1, const float* __restrict__ g1, const float* __restrict__ b1,
    const float* __restrict__ wout, const float* __restrict__ gout, const float* __restrict__ bout,
    float* __restrict__ wsf, unsigned short* __restrict__ whi, unsigned short* __restrict__ wlo,
    float4* __restrict__ xq) {
  const float rs = 1.0f / sqrtf(1.0f + 1e-5f);
  int t = blockIdx.x * 256 + threadIdx.x;
  if (t < 384) wsf[OFF_W0S + t] = w0[t] * (g0[t / 6] * rs);
  if (t < 64) {
    wsf[OFF_B0F + t] = b0[t];
    wsf[OFF_S1F + t] = g1[t] * rs;
    wsf[OFF_B1F + t] = b1[t];
  }
  if (t < 192) wsf[OFF_WOUTS + t] = wout[t] * (gout[t / 64] * rs);
  if (t < 3) wsf[OFF_BOUTF + t] = bout[t];
  if (t < BATCH * NPTS) {
    int bb = t >> 12, j = t & (NPTS - 1);
    const float* xb = x + bb * 3 * NPTS;
    float x0 = xb[j], x1 = xb[NPTS + j], x2 = xb[2 * NPTS + j];
    float xx = x0 * x0 + x1 * x1 + x2 * x2;
    xq[t] = make_float4(x0, x1, x2, xx);
  }
  // B-fragment layout for mfma_f32_16x16x32_bf16: frag ft = kk*4+nt; lane L holds
  // B[k = kk*32 + (L>>4)*8 + j][n = nt*16 + (L&15)], j packed consecutively.
  if (t < 24576) {
    int j = t & 7, L = (t >> 3) & 63, ft = t >> 9;
    int kk = ft >> 2, nt = ft & 3;
    int k = kk * 32 + ((L >> 4) << 3) + j;
    int c = k >> 6, d = k & 63;
    int o = nt * 16 + (L & 15);
    float w = w1[(o * 6 + c) * 64 + d];
    unsigned bw = __float_as_uint(w);
    unsigned hb = bw & 0xFFFF0000u;
    float r = w - __uint_as_float(hb);
    whi[t] = (unsigned short)(bw >> 16);
    wlo[t] = (unsigned short)(__float_as_uint(r) >> 16);
  }
}

// knn v6: R10's v2.1 with a u32 fast-path butterfly in phase B.
// The full u64 butterfly (6 x [2 shfl + u64 cmp + 2 cndmask]) is only needed
// when two candidates share identical pd BITS (rare, random data). Fast path:
// max-reduce the 32-bit high words (1 shfl + 1 v_max_u32 per step), then
// ballot(hk==best): popcount==1 (typical) -> winner unique, reconstruct full
// key via one readlane; else wave-uniform fallback to the exact u64 butterfly.
// Selection set provably identical.
__global__ __launch_bounds__(64, 4) void knn_kernel(const float4* __restrict__ xq,
                                                    unsigned short* __restrict__ idxbuf) {
  const int pt = blockIdx.x;
  const int b = pt >> 12, n = pt & (NPTS - 1);
  const int lane = threadIdx.x;
  const float4* xqb = xq + b * NPTS;
  const float4 xin = xqb[n];
  const float xi0 = xin.x, xi1 = xin.y, xi2 = xin.z;
  const float nxxi = -xin.w;

  u64 k1 = 0, k2 = 0;
  unsigned lo = 4095u - (unsigned)lane;
#pragma unroll 8
  for (int s = 0; s < 64; ++s) {
    float4 q = xqb[s * 64 + lane];
    float dot = xi0 * q.x + xi1 * q.y + xi2 * q.z;
    float pd = fmaf(2.0f, dot, nxxi) - q.w;   // bit-identical to ref expr
    u64 k = ((u64)(~__float_as_uint(pd)) << 32) | lo;
    lo -= 64u;
    bool c1 = k > k1;
    bool c2 = k > k2;
    u64 t = c1 ? k1 : k;
    k2 = c2 ? t : k2;
    k1 = c1 ? k : k1;
  }

  u64 tk = 0;
  unsigned myout = 0;
#pragma unroll 1
  for (int r = 0; r < KNN; ++r) {
    // ---- u32 fast-path argmax ----
    unsigned hk = (unsigned)(k1 >> 32);
    unsigned bh = hk;
    for (int off = 32; off > 0; off >>= 1) {
      unsigned oh = (unsigned)__shfl_xor((int)bh, off);
      bh = oh > bh ? oh : bh;                 // v_max_u32
    }
    u64 tiem = __ballot(hk == bh);
    u64 bk;
    if (__popcll(tiem) == 1) {                // unique high word (typical); uniform branch
      int wl = __ffsll(tiem) - 1;
      unsigned lowv = (unsigned)__shfl((int)(unsigned)(k1 & 0xFFFFFFFFu), wl);
      bk = ((u64)bh << 32) | lowv;
    } else {                                  // rare: pd-bit tie -> exact u64 butterfly
      u64 t = (hk == bh) ? k1 : 0;
      for (int off = 32; off > 0; off >>= 1) {
        u64 ok = shflx64(t, off);
        if (ok > t) t = ok;
      }
      bk = t;
    }
    unsigned bj = 4095u - (unsigned)(bk & 4095u);
    if (lane == r) myout = bj;
    bool owner = (k1 == bk);
    u64 bit = 1ull << (bj >> 6);
    if (owner) {
      tk |= bit;
      k1 = k2;
      k2 = 0;
    }
    bool need = owner && (k1 == 0);
    u64 nm = __ballot(need);
    if (nm) {
      int LN = __ffsll(nm) - 1;
      int j2 = lane * 64 + LN;
      float4 q = xqb[j2];
      float dot = xi0 * q.x + xi1 * q.y + xi2 * q.z;
      float pd = fmaf(2.0f, dot, nxxi) - q.w;
      u64 kk = ((u64)(~__float_as_uint(pd)) << 32) | (4095u - (unsigned)j2);
      u64 tkl = shflbc64(tk, LN);
      if ((tkl >> lane) & 1) kk = 0;
      u64 w1k = kk;
      for (int off = 32; off > 0; off >>= 1) {
        u64 ok = shflx64(w1k, off);
        if (ok > w1k) w1k = ok;
      }
      u64 kk2 = (kk == w1k) ? 0 : kk;
      u64 w2k = kk2;
      for (int off = 32; off > 0; off >>= 1) {
        u64 ok = shflx64(w2k, off);
        if (ok > w2k) w2k = ok;
      }
      if (lane == LN) { k1 = w1k; k2 = w2k; }
    }
  }
  if (lane < KNN) idxbuf[pt * KNN + lane] = (unsigned short)myout;
}

// mlp v4 (R10 exact — best measured config): hh-outer K-order, 40-reg h
// fragments, explicit B double-buffer, 5 M-tiles/wave, launch_bounds(64,2).
__global__ __launch_bounds__(64, 2) void mlp_kernel(const float4* __restrict__ xq,
                                                    const float* __restrict__ wsf,
                                                    const unsigned short* __restrict__ whi,
                                                    const unsigned short* __restrict__ wlo,
                                                    const unsigned short* __restrict__ idxbuf,
                                                    float* __restrict__ out) {
  __shared__ float w0l[448];
  __shared__ float v6l[80 * 12];
  __shared__ float pmax[20 * 66];

  const int lane = threadIdx.x;
  const int quad = lane >> 4, l15 = lane & 15;
  const int pt_base = blockIdx.x * 4;

  const i32x4* whp = (const i32x4*)whi;
  const i32x4* wlp = (const i32x4*)wlo;

  i32x4 wh[4], wl[4];
#pragma unroll
  for (int nt = 0; nt < 4; ++nt) {
    wh[nt] = whp[nt * 64 + lane];
    wl[nt] = wlp[nt * 64 + lane];
  }

  for (int i = lane; i < 448; i += 64) w0l[i] = wsf[i];

#pragma unroll
  for (int rep = 0; rep < 2; ++rep) {
    int e = rep * 64 + lane;
    if (e < 80) {
      int p = e / 20, el = e - p * 20;
      int pt = pt_base + p;
      int b = pt >> 12, n = pt & (NPTS - 1);
      float4 xi = xq[b * NPTS + n];
      int jn = idxbuf[pt * KNN + el];
      float4 xj = xq[b * NPTS + jn];
      v6l[e * 12 + 0] = xj.x - xi.x;
      v6l[e * 12 + 1] = xj.y - xi.y;
      v6l[e * 12 + 2] = xj.z - xi.z;
      v6l[e * 12 + 3] = xi.x;
      v6l[e * 12 + 4] = xi.y;
      v6l[e * 12 + 5] = xi.z;
    }
  }
  __syncthreads();

  f32x4 acc[5][4];
#pragma unroll
  for (int t = 0; t < 5; ++t)
#pragma unroll
    for (int nt = 0; nt < 4; ++nt) acc[t][nt] = (f32x4){0.f, 0.f, 0.f, 0.f};

#pragma unroll 1
  for (int hh = 0; hh < 2; ++hh) {
    float v6r[5][6];
#pragma unroll
    for (int t = 0; t < 5; ++t) {
      const float* vr = v6l + (t * 16 + l15) * 12;
      f32x4 a4 = *(const f32x4*)vr;
      v6r[t][0] = a4.x; v6r[t][1] = a4.y; v6r[t][2] = a4.z; v6r[t][3] = a4.w;
      v6r[t][4] = vr[4]; v6r[t][5] = vr[5];
    }
    float hf[5][8];
#pragma unroll
    for (int j = 0; j < 8; ++j) {
      const int d = hh * 32 + quad * 8 + j;
      const float* wr = w0l + d * 6;
      float wc0 = wr[0], wc1 = wr[1], wc2 = wr[2];
      float wc3 = wr[3], wc4 = wr[4], wc5 = wr[5];
      float bb = w0l[384 + d];
#pragma unroll
      for (int t = 0; t < 5; ++t) {
        float a = bb + wc0 * v6r[t][0] + wc1 * v6r[t][1] + wc2 * v6r[t][2]
                     + wc3 * v6r[t][3] + wc4 * v6r[t][4] + wc5 * v6r[t][5];
        hf[t][j] = fmaxf(a, 0.2f * a);
      }
    }

#pragma unroll 1
    for (int cc = 0; cc < 6; ++cc) {
      const int kk = cc * 2 + hh;
      const bool hasnext = !(hh == 1 && cc == 5);
      const int kkn = (cc < 5) ? kk + 2 : 1;
      i32x4 whn[4], wln[4];
      if (hasnext) {
#pragma unroll
        for (int nt = 0; nt < 4; ++nt) {
          whn[nt] = whp[(kkn * 4 + nt) * 64 + lane];
          wln[nt] = wlp[(kkn * 4 + nt) * 64 + lane];
        }
      }
#pragma unroll
      for (int t = 0; t < 5; ++t) {
        float vc = v6l[(t * 16 + l15) * 12 + cc];
        float u0 = vc * hf[t][0], u1 = vc * hf[t][1];
        float u2 = vc * hf[t][2], u3 = vc * hf[t][3];
        float u4 = vc * hf[t][4], u5 = vc * hf[t][5];
        float u6 = vc * hf[t][6], u7 = vc * hf[t][7];
        unsigned ub0 = __float_as_uint(u0), ub1 = __float_as_uint(u1);
        unsigned ub2 = __float_as_uint(u2), ub3 = __float_as_uint(u3);
        unsigned ub4 = __float_as_uint(u4), ub5 = __float_as_uint(u5);
        unsigned ub6 = __float_as_uint(u6), ub7 = __float_as_uint(u7);
        float r0 = u0 - __uint_as_float(ub0 & 0xFFFF0000u);
        float r1 = u1 - __uint_as_float(ub1 & 0xFFFF0000u);
        float r2 = u2 - __uint_as_float(ub2 & 0xFFFF0000u);
        float r3 = u3 - __uint_as_float(ub3 & 0xFFFF0000u);
        float r4 = u4 - __uint_as_float(ub4 & 0xFFFF0000u);
        float r5 = u5 - __uint_as_float(ub5 & 0xFFFF0000u);
        float r6 = u6 - __uint_as_float(ub6 & 0xFFFF0000u);
        float r7 = u7 - __uint_as_float(ub7 & 0xFFFF0000u);
        i32x4 ah, al;
        ah.x = __builtin_amdgcn_perm(ub1, ub0, 0x07060302);
        ah.y = __builtin_amdgcn_perm(ub3, ub2, 0x07060302);
        ah.z = __builtin_amdgcn_perm(ub5, ub4, 0x07060302);
        ah.w = __builtin_amdgcn_perm(ub7, ub6, 0x07060302);
        al.x = __builtin_amdgcn_perm(__float_as_uint(r1), __float_as_uint(r0), 0x07060302);
        al.y = __builtin_amdgcn_perm(__float_as_uint(r3), __float_as_uint(r2), 0x07060302);
        al.z = __builtin_amdgcn_perm(__float_as_uint(r5), __float_as_uint(r4), 0x07060302);
        al.w = __builtin_amdgcn_perm(__float_as_uint(r7), __float_as_uint(r6), 0x07060302);
        bf16x8 ahv = __builtin_bit_cast(bf16x8, ah);
        bf16x8 alv = __builtin_bit_cast(bf16x8, al);
#pragma unroll
        for (int nt = 0; nt < 4; ++nt) {
          bf16x8 bh = __builtin_bit_cast(bf16x8, wh[nt]);
          bf16x8 bl = __builtin_bit_cast(bf16x8, wl[nt]);
          acc[t][nt] = __builtin_amdgcn_mfma_f32_16x16x32_bf16(ahv, bh, acc[t][nt], 0, 0, 0);
          acc[t][nt] = __builtin_amdgcn_mfma_f32_16x16x32_bf16(ahv, bl, acc[t][nt], 0, 0, 0);
          acc[t][nt] = __builtin_amdgcn_mfma_f32_16x16x32_bf16(alv, bh, acc[t][nt], 0, 0, 0);
        }
      }
      if (hasnext) {
#pragma unroll
        for (int nt = 0; nt < 4; ++nt) { wh[nt] = whn[nt]; wl[nt] = wln[nt]; }
      }
    }
  }
  __syncthreads();

  float s1v[4], b1v[4];
#pragma unroll
  for (int nt = 0; nt < 4; ++nt) {
    s1v[nt] = wsf[OFF_S1F + nt * 16 + l15];
    b1v[nt] = wsf[OFF_B1F + nt * 16 + l15];
  }
#pragma unroll
  for (int t = 0; t < 5; ++t) {
#pragma unroll
    for (int nt = 0; nt < 4; ++nt) {
      f32x4 a = acc[t][nt];
      float z0 = a.x * s1v[nt] + b1v[nt]; z0 = fmaxf(z0, 0.2f * z0);
      float z1 = a.y * s1v[nt] + b1v[nt]; z1 = fmaxf(z1, 0.2f * z1);
      float z2 = a.z * s1v[nt] + b1v[nt]; z2 = fmaxf(z2, 0.2f * z2);
      float z3 = a.w * s1v[nt] + b1v[nt]; z3 = fmaxf(z3, 0.2f * z3);
      float m4 = fmaxf(fmaxf(z0, z1), fmaxf(z2, z3));
      pmax[(t * 4 + quad) * 66 + nt * 16 + l15] = m4;
    }
  }
  __syncthreads();

  float woutr[3];
#pragma unroll
  for (int m = 0; m < 3; ++m) woutr[m] = wsf[OFF_WOUTS + m * 64 + lane];
#pragma unroll
  for (int p = 0; p < 4; ++p) {
    float x1 = pmax[(p * 5 + 0) * 66 + lane];
    x1 = fmaxf(x1, pmax[(p * 5 + 1) * 66 + lane]);
    x1 = fmaxf(x1, pmax[(p * 5 + 2) * 66 + lane]);
    x1 = fmaxf(x1, pmax[(p * 5 + 3) * 66 + lane]);
    x1 = fmaxf(x1, pmax[(p * 5 + 4) * 66 + lane]);
    int pt = pt_base + p;
    int b = pt >> 12, n = pt & (NPTS - 1);
#pragma unroll
    for (int m = 0; m < 3; ++m) {
      float part = woutr[m] * x1;
      for (int off = 32; off > 0; off >>= 1) part += __shfl_xor(part, off);
      if (lane == 0) {
        float ov = part + wsf[OFF_BOUTF + m];
        out[(b * 3 + m) * NPTS + n] = fmaxf(ov, 0.2f * ov);
      }
    }
  }
}

extern "C" void kernel_launch(void* const* d_in, const int* in_sizes, int n_in,
                              void* d_out, int out_size, void* d_ws, size_t ws_size,
                              hipStream_t stream) {
  const float* x    = (const float*)d_in[0];
  const float* w0   = (const float*)d_in[1];
  const float* g0   = (const float*)d_in[2];
  const float* b0   = (const float*)d_in[3];
  const float* w1   = (const float*)d_in[4];
  const float* g1   = (const float*)d_in[5];
  const float* b1   = (const float*)d_in[6];
  const float* wout = (const float*)d_in[7];
  const float* gout = (const float*)d_in[8];
  const float* bout = (const float*)d_in[9];
  float* wsf = (float*)d_ws;
  unsigned short* whi = (unsigned short*)((char*)d_ws + OFF_WHI_BYTES);
  unsigned short* wlo = (unsigned short*)((char*)d_ws + OFF_WLO_BYTES);
  unsigned short* idxbuf = (unsigned short*)((char*)d_ws + OFF_IDX_BYTES);
  float4* xq = (float4*)((char*)d_ws + OFF_XQ_BYTES);
  float* out = (float*)d_out;

  prep_kernel<<<96, 256, 0, stream>>>(x, w0, g0, b0, w1, g1, b1, wout, gout, bout,
                                      wsf, whi, wlo, xq);
  knn_kernel<<<BATCH * NPTS, 64, 0, stream>>>(xq, idxbuf);
  mlp_kernel<<<BATCH * NPTS / 4, 64, 0, stream>>>(xq, wsf, whi, wlo, idxbuf, out);
}

// Round 15
// 166.875 us; speedup vs baseline: 1.1334x; 1.0606x over previous
//
#include <hip/hip_runtime.h>
#include <hip/hip_bf16.h>

#define NPTS 4096
#define BATCH 4
#define KNN 20

typedef __attribute__((ext_vector_type(8))) short bf16x8;
typedef __attribute__((ext_vector_type(4))) float f32x4;
typedef __attribute__((ext_vector_type(4))) int i32x4;
typedef unsigned long long u64;

// ws layout (bytes):
//   0      : fp32 tables: w0s[384] b0[64] s1[64] b1[64] wouts[192] bout[3]
//   4096   : whi frags ushort[24576]  (B-fragment layout, hi split)
//   53248  : wlo frags ushort[24576]  (lo split)
//   102400 : idxbuf ushort[16384*20]  (655360 B)
//   757760 : xq float4[16384] = (x0,x1,x2,||x||^2)
#define OFF_W0S   0
#define OFF_B0F   384
#define OFF_S1F   448
#define OFF_B1F   512
#define OFF_WOUTS 576
#define OFF_BOUTF 768
#define OFF_WHI_BYTES 4096
#define OFF_WLO_BYTES 53248
#define OFF_IDX_BYTES 102400
#define OFF_XQ_BYTES  757760

__device__ __forceinline__ u64 shflx64(u64 v, int off) {
  int lo = __shfl_xor((int)(v & 0xFFFFFFFFull), off);
  int hi = __shfl_xor((int)(v >> 32), off);
  return ((u64)(unsigned)hi << 32) | (unsigned)lo;
}
__device__ __forceinline__ u64 shflbc64(u64 v, int src) {
  int lo = __shfl((int)(v & 0xFFFFFFFFull), src);
  int hi = __shfl((int)(v >> 32), src);
  return ((u64)(unsigned)hi << 32) | (unsigned)lo;
}

// Wave64 max-reduce via DPP (row_shr 1,2,4,8 + row_bcast15/31); lane 63 holds
// the max, broadcast via readlane. Keys are always > 0 so bound_ctrl/masked
// zeros are identity for unsigned max.
__device__ __forceinline__ unsigned dpp_wave_max(unsigned v) {
  unsigned t;
  t = (unsigned)__builtin_amdgcn_update_dpp(0, (int)v, 0x111, 0xF, 0xF, true); v = v > t ? v : t;
  t = (unsigned)__builtin_amdgcn_update_dpp(0, (int)v, 0x112, 0xF, 0xF, true); v = v > t ? v : t;
  t = (unsigned)__builtin_amdgcn_update_dpp(0, (int)v, 0x114, 0xF, 0xF, true); v = v > t ? v : t;
  t = (unsigned)__builtin_amdgcn_update_dpp(0, (int)v, 0x118, 0xF, 0xF, true); v = v > t ? v : t;
  t = (unsigned)__builtin_amdgcn_update_dpp(0, (int)v, 0x142, 0xA, 0xF, true); v = v > t ? v : t;
  t = (unsigned)__builtin_amdgcn_update_dpp(0, (int)v, 0x143, 0xC, 0xF, true); v = v > t ? v : t;
  return (unsigned)__builtin_amdgcn_readlane((int)v, 63);
}

__global__ __launch_bounds__(256) void prep_kernel(
    const float* __restrict__ x,
    const float* __restrict__ w0, const float* __restrict__ g0, const float* __restrict__ b0,
    const float* __restrict__ w1, const float* __restrict__ g1, const float* __restrict__ b1,
    const float* __restrict__ wout, const float* __restrict__ gout, const float* __restrict__ bout,
    float* __restrict__ wsf, unsigned short* __restrict__ whi, unsigned short* __restrict__ wlo,
    float4* __restrict__ xq) {
  const float rs = 1.0f / sqrtf(1.0f + 1e-5f);
  int t = blockIdx.x * 256 + threadIdx.x;
  if (t < 384) wsf[OFF_W0S + t] = w0[t] * (g0[t / 6] * rs);
  if (t < 64) {
    wsf[OFF_B0F + t] = b0[t];
    wsf[OFF_S1F + t] = g1[t] * rs;
    wsf[OFF_B1F + t] = b1[t];
  }
  if (t < 192) wsf[OFF_WOUTS + t] = wout[t] * (gout[t / 64] * rs);
  if (t < 3) wsf[OFF_BOUTF + t] = bout[t];
  if (t < BATCH * NPTS) {
    int bb = t >> 12, j = t & (NPTS - 1);
    const float* xb = x + bb * 3 * NPTS;
    float x0 = xb[j], x1 = xb[NPTS + j], x2 = xb[2 * NPTS + j];
    float xx = x0 * x0 + x1 * x1 + x2 * x2;
    xq[t] = make_float4(x0, x1, x2, xx);
  }
  // B-fragment layout for mfma_f32_16x16x32_bf16: frag ft = kk*4+nt; lane L holds
  // B[k = kk*32 + (L>>4)*8 + j][n = nt*16 + (L&15)], j packed consecutively.
  if (t < 24576) {
    int j = t & 7, L = (t >> 3) & 63, ft = t >> 9;
    int kk = ft >> 2, nt = ft & 3;
    int k = kk * 32 + ((L >> 4) << 3) + j;
    int c = k >> 6, d = k & 63;
    int o = nt * 16 + (L & 15);
    float w = w1[(o * 6 + c) * 64 + d];
    unsigned bw = __float_as_uint(w);
    unsigned hb = bw & 0xFFFF0000u;
    float r = w - __uint_as_float(hb);
    whi[t] = (unsigned short)(bw >> 16);
    wlo[t] = (unsigned short)(__float_as_uint(r) >> 16);
  }
}

// knn v7: phase A top-2 cache as (u32 key=~bits(pd), u32 j) pairs (u32 cmps,
// in-order strict > keeps lax.top_k tie order); phase B fast path = DPP
// max-reduce (no ds_swizzle chain) + owner ds_write of winner j to an LDS
// slot (no broadcast shuffle, no lane==r bookkeeping). pd-bit ties (rare) ->
// min-j shuffle reduce; cache exhaustion (rare) -> u64 rescan (unchanged).
__global__ __launch_bounds__(64, 4) void knn_kernel(const float4* __restrict__ xq,
                                                    unsigned short* __restrict__ idxbuf) {
  __shared__ unsigned outj[KNN];
  const int pt = blockIdx.x;
  const int b = pt >> 12, n = pt & (NPTS - 1);
  const int lane = threadIdx.x;
  const float4* xqb = xq + b * NPTS;
  const float4 xin = xqb[n];
  const float xi0 = xin.x, xi1 = xin.y, xi2 = xin.z;
  const float nxxi = -xin.w;

  // phase A: single scan, per-lane top-2
  unsigned h1 = 0, j1c = 0, h2 = 0, j2c = 0;
  unsigned jj = (unsigned)lane;
#pragma unroll 8
  for (int s = 0; s < 64; ++s) {
    float4 q = xqb[s * 64 + lane];
    float dot = xi0 * q.x + xi1 * q.y + xi2 * q.z;
    float pd = fmaf(2.0f, dot, nxxi) - q.w;    // bit-identical to ref expr
    unsigned h = ~__float_as_uint(pd);         // monotone key, always > 0
    bool c1 = h > h1;
    bool c2 = h > h2;
    unsigned th = c1 ? h1 : h;
    unsigned tj = c1 ? j1c : jj;
    h2 = c2 ? th : h2;  j2c = c2 ? tj : j2c;
    h1 = c1 ? h : h1;   j1c = c1 ? jj : j1c;
    jj += 64u;
  }

  // phase B: 20 rounds of argmax + pop
  u64 tk = 0;
#pragma unroll 1
  for (int r = 0; r < KNN; ++r) {
    unsigned bh = dpp_wave_max(h1);
    u64 tiem = __ballot(h1 == bh);
    int wl;
    if (__popcll(tiem) > 1) {        // rare: identical pd bits -> smallest j wins
      unsigned jm = (h1 == bh) ? j1c : 0xFFFFFFFFu;
      for (int off = 32; off > 0; off >>= 1) {
        unsigned oj = (unsigned)__shfl_xor((int)jm, off);
        jm = oj < jm ? oj : jm;
      }
      wl = __ffsll(__ballot(h1 == bh && j1c == jm)) - 1;
    } else {
      wl = __ffsll(tiem) - 1;
    }
    bool owner = (lane == wl);
    if (owner) {
      outj[r] = j1c;                 // fire-and-forget; read after the loop
      tk |= 1ull << (j1c >> 6);
      h1 = h2; j1c = j2c; h2 = 0;
    }
    bool need = owner && (h1 == 0);
    u64 nm = __ballot(need);
    if (nm) {                        // rare: owner's cache exhausted -> u64 rescan
      int LN = __ffsll(nm) - 1;
      int jg = lane * 64 + LN;       // lane s rescans slot s of lane LN
      float4 q = xqb[jg];
      float dot = xi0 * q.x + xi1 * q.y + xi2 * q.z;
      float pd = fmaf(2.0f, dot, nxxi) - q.w;
      u64 kk = ((u64)(~__float_as_uint(pd)) << 32) | (4095u - (unsigned)jg);
      u64 tkl = shflbc64(tk, LN);
      if ((tkl >> lane) & 1) kk = 0;
      u64 w1k = kk;
      for (int off = 32; off > 0; off >>= 1) {
        u64 ok = shflx64(w1k, off);
        if (ok > w1k) w1k = ok;
      }
      u64 kk2 = (kk == w1k) ? 0 : kk;
      u64 w2k = kk2;
      for (int off = 32; off > 0; off >>= 1) {
        u64 ok = shflx64(w2k, off);
        if (ok > w2k) w2k = ok;
      }
      if (lane == LN) {
        h1 = (unsigned)(w1k >> 32); j1c = 4095u - (unsigned)(w1k & 4095u);
        h2 = (unsigned)(w2k >> 32); j2c = 4095u - (unsigned)(w2k & 4095u);
      }
    }
  }
  __syncthreads();
  if (lane < KNN) idxbuf[pt * KNN + lane] = (unsigned short)outj[lane];
}

// mlp v4 (R10 exact — best measured config): hh-outer K-order, 40-reg h
// fragments, explicit B double-buffer, 5 M-tiles/wave, launch_bounds(64,2).
__global__ __launch_bounds__(64, 2) void mlp_kernel(const float4* __restrict__ xq,
                                                    const float* __restrict__ wsf,
                                                    const unsigned short* __restrict__ whi,
                                                    const unsigned short* __restrict__ wlo,
                                                    const unsigned short* __restrict__ idxbuf,
                                                    float* __restrict__ out) {
  __shared__ float w0l[448];
  __shared__ float v6l[80 * 12];
  __shared__ float pmax[20 * 66];

  const int lane = threadIdx.x;
  const int quad = lane >> 4, l15 = lane & 15;
  const int pt_base = blockIdx.x * 4;

  const i32x4* whp = (const i32x4*)whi;
  const i32x4* wlp = (const i32x4*)wlo;

  i32x4 wh[4], wl[4];
#pragma unroll
  for (int nt = 0; nt < 4; ++nt) {
    wh[nt] = whp[nt * 64 + lane];
    wl[nt] = wlp[nt * 64 + lane];
  }

  for (int i = lane; i < 448; i += 64) w0l[i] = wsf[i];

#pragma unroll
  for (int rep = 0; rep < 2; ++rep) {
    int e = rep * 64 + lane;
    if (e < 80) {
      int p = e / 20, el = e - p * 20;
      int pt = pt_base + p;
      int b = pt >> 12, n = pt & (NPTS - 1);
      float4 xi = xq[b * NPTS + n];
      int jn = idxbuf[pt * KNN + el];
      float4 xj = xq[b * NPTS + jn];
      v6l[e * 12 + 0] = xj.x - xi.x;
      v6l[e * 12 + 1] = xj.y - xi.y;
      v6l[e * 12 + 2] = xj.z - xi.z;
      v6l[e * 12 + 3] = xi.x;
      v6l[e * 12 + 4] = xi.y;
      v6l[e * 12 + 5] = xi.z;
    }
  }
  __syncthreads();

  f32x4 acc[5][4];
#pragma unroll
  for (int t = 0; t < 5; ++t)
#pragma unroll
    for (int nt = 0; nt < 4; ++nt) acc[t][nt] = (f32x4){0.f, 0.f, 0.f, 0.f};

#pragma unroll 1
  for (int hh = 0; hh < 2; ++hh) {
    float v6r[5][6];
#pragma unroll
    for (int t = 0; t < 5; ++t) {
      const float* vr = v6l + (t * 16 + l15) * 12;
      f32x4 a4 = *(const f32x4*)vr;
      v6r[t][0] = a4.x; v6r[t][1] = a4.y; v6r[t][2] = a4.z; v6r[t][3] = a4.w;
      v6r[t][4] = vr[4]; v6r[t][5] = vr[5];
    }
    float hf[5][8];
#pragma unroll
    for (int j = 0; j < 8; ++j) {
      const int d = hh * 32 + quad * 8 + j;
      const float* wr = w0l + d * 6;
      float wc0 = wr[0], wc1 = wr[1], wc2 = wr[2];
      float wc3 = wr[3], wc4 = wr[4], wc5 = wr[5];
      float bb = w0l[384 + d];
#pragma unroll
      for (int t = 0; t < 5; ++t) {
        float a = bb + wc0 * v6r[t][0] + wc1 * v6r[t][1] + wc2 * v6r[t][2]
                     + wc3 * v6r[t][3] + wc4 * v6r[t][4] + wc5 * v6r[t][5];
        hf[t][j] = fmaxf(a, 0.2f * a);
      }
    }

#pragma unroll 1
    for (int cc = 0; cc < 6; ++cc) {
      const int kk = cc * 2 + hh;
      const bool hasnext = !(hh == 1 && cc == 5);
      const int kkn = (cc < 5) ? kk + 2 : 1;
      i32x4 whn[4], wln[4];
      if (hasnext) {
#pragma unroll
        for (int nt = 0; nt < 4; ++nt) {
          whn[nt] = whp[(kkn * 4 + nt) * 64 + lane];
          wln[nt] = wlp[(kkn * 4 + nt) * 64 + lane];
        }
      }
#pragma unroll
      for (int t = 0; t < 5; ++t) {
        float vc = v6l[(t * 16 + l15) * 12 + cc];
        float u0 = vc * hf[t][0], u1 = vc * hf[t][1];
        float u2 = vc * hf[t][2], u3 = vc * hf[t][3];
        float u4 = vc * hf[t][4], u5 = vc * hf[t][5];
        float u6 = vc * hf[t][6], u7 = vc * hf[t][7];
        unsigned ub0 = __float_as_uint(u0), ub1 = __float_as_uint(u1);
        unsigned ub2 = __float_as_uint(u2), ub3 = __float_as_uint(u3);
        unsigned ub4 = __float_as_uint(u4), ub5 = __float_as_uint(u5);
        unsigned ub6 = __float_as_uint(u6), ub7 = __float_as_uint(u7);
        float r0 = u0 - __uint_as_float(ub0 & 0xFFFF0000u);
        float r1 = u1 - __uint_as_float(ub1 & 0xFFFF0000u);
        float r2 = u2 - __uint_as_float(ub2 & 0xFFFF0000u);
        float r3 = u3 - __uint_as_float(ub3 & 0xFFFF0000u);
        float r4 = u4 - __uint_as_float(ub4 & 0xFFFF0000u);
        float r5 = u5 - __uint_as_float(ub5 & 0xFFFF0000u);
        float r6 = u6 - __uint_as_float(ub6 & 0xFFFF0000u);
        float r7 = u7 - __uint_as_float(ub7 & 0xFFFF0000u);
        i32x4 ah, al;
        ah.x = __builtin_amdgcn_perm(ub1, ub0, 0x07060302);
        ah.y = __builtin_amdgcn_perm(ub3, ub2, 0x07060302);
        ah.z = __builtin_amdgcn_perm(ub5, ub4, 0x07060302);
        ah.w = __builtin_amdgcn_perm(ub7, ub6, 0x07060302);
        al.x = __builtin_amdgcn_perm(__float_as_uint(r1), __float_as_uint(r0), 0x07060302);
        al.y = __builtin_amdgcn_perm(__float_as_uint(r3), __float_as_uint(r2), 0x07060302);
        al.z = __builtin_amdgcn_perm(__float_as_uint(r5), __float_as_uint(r4), 0x07060302);
        al.w = __builtin_amdgcn_perm(__float_as_uint(r7), __float_as_uint(r6), 0x07060302);
        bf16x8 ahv = __builtin_bit_cast(bf16x8, ah);
        bf16x8 alv = __builtin_bit_cast(bf16x8, al);
#pragma unroll
        for (int nt = 0; nt < 4; ++nt) {
          bf16x8 bh = __builtin_bit_cast(bf16x8, wh[nt]);
          bf16x8 bl = __builtin_bit_cast(bf16x8, wl[nt]);
          acc[t][nt] = __builtin_amdgcn_mfma_f32_16x16x32_bf16(ahv, bh, acc[t][nt], 0, 0, 0);
          acc[t][nt] = __builtin_amdgcn_mfma_f32_16x16x32_bf16(ahv, bl, acc[t][nt], 0, 0, 0);
          acc[t][nt] = __builtin_amdgcn_mfma_f32_16x16x32_bf16(alv, bh, acc[t][nt], 0, 0, 0);
        }
      }
      if (hasnext) {
#pragma unroll
        for (int nt = 0; nt < 4; ++nt) { wh[nt] = whn[nt]; wl[nt] = wln[nt]; }
      }
    }
  }
  __syncthreads();

  float s1v[4], b1v[4];
#pragma unroll
  for (int nt = 0; nt < 4; ++nt) {
    s1v[nt] = wsf[OFF_S1F + nt * 16 + l15];
    b1v[nt] = wsf[OFF_B1F + nt * 16 + l15];
  }
#pragma unroll
  for (int t = 0; t < 5; ++t) {
#pragma unroll
    for (int nt = 0; nt < 4; ++nt) {
      f32x4 a = acc[t][nt];
      float z0 = a.x * s1v[nt] + b1v[nt]; z0 = fmaxf(z0, 0.2f * z0);
      float z1 = a.y * s1v[nt] + b1v[nt]; z1 = fmaxf(z1, 0.2f * z1);
      float z2 = a.z * s1v[nt] + b1v[nt]; z2 = fmaxf(z2, 0.2f * z2);
      float z3 = a.w * s1v[nt] + b1v[nt]; z3 = fmaxf(z3, 0.2f * z3);
      float m4 = fmaxf(fmaxf(z0, z1), fmaxf(z2, z3));
      pmax[(t * 4 + quad) * 66 + nt * 16 + l15] = m4;
    }
  }
  __syncthreads();

  float woutr[3];
#pragma unroll
  for (int m = 0; m < 3; ++m) woutr[m] = wsf[OFF_WOUTS + m * 64 + lane];
#pragma unroll
  for (int p = 0; p < 4; ++p) {
    float x1 = pmax[(p * 5 + 0) * 66 + lane];
    x1 = fmaxf(x1, pmax[(p * 5 + 1) * 66 + lane]);
    x1 = fmaxf(x1, pmax[(p * 5 + 2) * 66 + lane]);
    x1 = fmaxf(x1, pmax[(p * 5 + 3) * 66 + lane]);
    x1 = fmaxf(x1, pmax[(p * 5 + 4) * 66 + lane]);
    int pt = pt_base + p;
    int b = pt >> 12, n = pt & (NPTS - 1);
#pragma unroll
    for (int m = 0; m < 3; ++m) {
      float part = woutr[m] * x1;
      for (int off = 32; off > 0; off >>= 1) part += __shfl_xor(part, off);
      if (lane == 0) {
        float ov = part + wsf[OFF_BOUTF + m];
        out[(b * 3 + m) * NPTS + n] = fmaxf(ov, 0.2f * ov);
      }
    }
  }
}

extern "C" void kernel_launch(void* const* d_in, const int* in_sizes, int n_in,
                              void* d_out, int out_size, void* d_ws, size_t ws_size,
                              hipStream_t stream) {
  const float* x    = (const float*)d_in[0];
  const float* w0   = (const float*)d_in[1];
  const float* g0   = (const float*)d_in[2];
  const float* b0   = (const float*)d_in[3];
  const float* w1   = (const float*)d_in[4];
  const float* g1   = (const float*)d_in[5];
  const float* b1   = (const float*)d_in[6];
  const float* wout = (const float*)d_in[7];
  const float* gout = (const float*)d_in[8];
  const float* bout = (const float*)d_in[9];
  float* wsf = (float*)d_ws;
  unsigned short* whi = (unsigned short*)((char*)d_ws + OFF_WHI_BYTES);
  unsigned short* wlo = (unsigned short*)((char*)d_ws + OFF_WLO_BYTES);
  unsigned short* idxbuf = (unsigned short*)((char*)d_ws + OFF_IDX_BYTES);
  float4* xq = (float4*)((char*)d_ws + OFF_XQ_BYTES);
  float* out = (float*)d_out;

  prep_kernel<<<96, 256, 0, stream>>>(x, w0, g0, b0, w1, g1, b1, wout, gout, bout,
                                      wsf, whi, wlo, xq);
  knn_kernel<<<BATCH * NPTS, 64, 0, stream>>>(xq, idxbuf);
  mlp_kernel<<<BATCH * NPTS / 4, 64, 0, stream>>>(xq, wsf, whi, wlo, idxbuf, out);
}